// Round 2
// baseline (198.199 us; speedup 1.0000x reference)
//
#include <hip/hip_runtime.h>
#include <hip/hip_bf16.h>
#include <cstdint>

#define T_TOK 4096
#define D_DIM 1024
#define E_EXP 8
#define CAP   640          // int(1.25 * 4096 / 8)
#define NBIN  64

typedef __attribute__((ext_vector_type(8))) short short8;
typedef __attribute__((ext_vector_type(4))) float f32x4;

// round-to-nearest-even float -> bf16 bits
__device__ inline unsigned short f2bf(float f) {
    uint32_t u = __float_as_uint(f);
    u += 0x7fffu + ((u >> 16) & 1u);
    return (unsigned short)(u >> 16);
}

// ---------------- zero out + zero bins ----------------
__global__ void zero_out_kernel(float* __restrict__ out,
                                float* __restrict__ ppart, float* __restrict__ fpart) {
    size_t i = (size_t)blockIdx.x * 256 + threadIdx.x;   // float4 index
    float4 z = {0.f, 0.f, 0.f, 0.f};
    ((float4*)out)[i] = z;                                // grid covers T*D/4 exactly
    if (i == 0) out[(size_t)T_TOK * D_DIM] = 0.f;         // aux slot
    if (i < NBIN * 8) { ppart[i] = 0.f; fpart[i] = 0.f; }
}

// ---------------- gating: logits, softmax, argmax, binned f/P sums ----------------
__global__ __launch_bounds__(256) void gating_kernel(
    const float* __restrict__ x, const float* __restrict__ Wg,
    const float* __restrict__ bg,
    int* __restrict__ top_idx, float* __restrict__ top_prob,
    float* __restrict__ ppart, float* __restrict__ fpart)
{
    int wid  = threadIdx.x >> 6;
    int lane = threadIdx.x & 63;
    int t = blockIdx.x * 4 + wid;     // one wave per token

    float acc[8];
    #pragma unroll
    for (int e = 0; e < 8; e++) acc[e] = 0.f;

    const float* xr = x + (size_t)t * D_DIM;
    #pragma unroll 4
    for (int i = 0; i < 16; i++) {
        int d = lane + 64 * i;
        float xv = xr[d];
        const float4* wr = (const float4*)(Wg + (size_t)d * 8);
        float4 w0 = wr[0], w1 = wr[1];
        acc[0] += xv * w0.x; acc[1] += xv * w0.y;
        acc[2] += xv * w0.z; acc[3] += xv * w0.w;
        acc[4] += xv * w1.x; acc[5] += xv * w1.y;
        acc[6] += xv * w1.z; acc[7] += xv * w1.w;
    }
    #pragma unroll
    for (int off = 32; off > 0; off >>= 1) {
        #pragma unroll
        for (int e = 0; e < 8; e++) acc[e] += __shfl_xor(acc[e], off, 64);
    }

    if (lane == 0) {
        float lg[8];
        #pragma unroll
        for (int e = 0; e < 8; e++) lg[e] = acc[e] + bg[e];
        float m = lg[0]; int am = 0;
        #pragma unroll
        for (int e = 1; e < 8; e++) { if (lg[e] > m) { m = lg[e]; am = e; } }
        float ex[8], s = 0.f;
        #pragma unroll
        for (int e = 0; e < 8; e++) { ex[e] = expf(lg[e] - m); s += ex[e]; }
        float inv = 1.f / s;
        top_idx[t]  = am;
        top_prob[t] = ex[am] * inv;
        int bin = (int)(blockIdx.x & (NBIN - 1));
        #pragma unroll
        for (int e = 0; e < 8; e++) atomicAdd(&ppart[bin * 8 + e], ex[e] * inv);
        atomicAdd(&fpart[bin * 8 + am], 1.0f);
    }
}

// ---------------- scan: exact token-order capacity dispatch ----------------
__global__ void scan_kernel(const int* __restrict__ top_idx,
                            int* __restrict__ tok_list, int* __restrict__ cnt)
{
    int lane = threadIdx.x;           // 64 threads, single wave
    int base[8];
    #pragma unroll
    for (int q = 0; q < 8; q++) base[q] = 0;
    unsigned long long ltmask = (lane == 0) ? 0ull : ((~0ull) >> (64 - lane));

    for (int c = 0; c < T_TOK / 64; c++) {
        int t = c * 64 + lane;
        int e = top_idx[t];
        int pos = 0, tot[8];
        #pragma unroll
        for (int q = 0; q < 8; q++) {
            unsigned long long mk = __ballot(e == q);
            if (e == q) pos = base[q] + __popcll(mk & ltmask);
            tot[q] = __popcll(mk);
        }
        if (pos < CAP) tok_list[e * CAP + pos] = t;
        #pragma unroll
        for (int q = 0; q < 8; q++) base[q] += tot[q];
    }
    if (lane < 8) cnt[lane] = base[lane] < CAP ? base[lane] : CAP;
}

// ---------------- staging helper: global fp32 -> LDS bf16 ----------------
__device__ inline void stage_tile(const float* __restrict__ x,
                                  const float* __restrict__ We,
                                  const int* rowtok, int k0,
                                  int a_c4, int a_r0, int b_n4, int b_kb,
                                  short* Als, short* Bls)
{
    // A: gathered token rows, [m][k] stride 40
    #pragma unroll
    for (int i = 0; i < 4; i++) {
        const float4 xv = *(const float4*)(x + (size_t)rowtok[i] * D_DIM + k0 + 4 * a_c4);
        ushort4 us;
        us.x = f2bf(xv.x); us.y = f2bf(xv.y); us.z = f2bf(xv.z); us.w = f2bf(xv.w);
        *(ushort4*)&Als[(a_r0 + 32 * i) * 40 + 4 * a_c4] = us;
    }
    // B transposed: [n][k] stride 40
    const float* wp = We + (size_t)(k0 + b_kb) * D_DIM + 4 * b_n4;
    float4 w0 = *(const float4*)(wp);
    float4 w1 = *(const float4*)(wp + 1024);
    float4 w2 = *(const float4*)(wp + 2048);
    float4 w3 = *(const float4*)(wp + 3072);
    ushort4 u0, u1, u2, u3;
    u0.x = f2bf(w0.x); u0.y = f2bf(w1.x); u0.z = f2bf(w2.x); u0.w = f2bf(w3.x);
    u1.x = f2bf(w0.y); u1.y = f2bf(w1.y); u1.z = f2bf(w2.y); u1.w = f2bf(w3.y);
    u2.x = f2bf(w0.z); u2.y = f2bf(w1.z); u2.z = f2bf(w2.z); u2.w = f2bf(w3.z);
    u3.x = f2bf(w0.w); u3.y = f2bf(w1.w); u3.z = f2bf(w2.w); u3.w = f2bf(w3.w);
    *(ushort4*)&Bls[(4 * b_n4 + 0) * 40 + b_kb] = u0;
    *(ushort4*)&Bls[(4 * b_n4 + 1) * 40 + b_kb] = u1;
    *(ushort4*)&Bls[(4 * b_n4 + 2) * 40 + b_kb] = u2;
    *(ushort4*)&Bls[(4 * b_n4 + 3) * 40 + b_kb] = u3;
}

// ---------------- expert GEMM: bf16 MFMA 128x128 tile, double-buffered LDS ----------------
__global__ __launch_bounds__(256) void expert_gemm(
    const float* __restrict__ x, const float* __restrict__ W,
    const float* __restrict__ bias,
    const int* __restrict__ tok_list, const int* __restrict__ cnt,
    const float* __restrict__ top_prob, float* __restrict__ out)
{
    int bid = blockIdx.x;
    int e   = bid / 40;               // 5 mt * 8 nt = 40 per expert
    int rem = bid % 40;
    int mt  = rem / 8, nt = rem % 8;
    int count = cnt[e];
    int m0 = mt * 128;
    if (m0 >= count) return;
    int n0 = nt * 128;

    __shared__ __attribute__((aligned(16))) short AlsBuf[2][128 * 40]; // 20 KB
    __shared__ __attribute__((aligned(16))) short BlsBuf[2][128 * 40]; // 20 KB

    int tid  = threadIdx.x;
    int lane = tid & 63, wid = tid >> 6;
    int quad = lane >> 4, l16 = lane & 15;
    int mB = (wid >> 1) * 64, nB = (wid & 1) * 64;

    f32x4 accf[4][4];
    #pragma unroll
    for (int i = 0; i < 4; i++)
        #pragma unroll
        for (int j = 0; j < 4; j++)
            accf[i][j] = (f32x4){0.f, 0.f, 0.f, 0.f};

    const int* tl = tok_list + e * CAP;
    int a_c4 = tid & 7, a_r0 = tid >> 3;          // A: 8 float4/row, 32 rows/iter
    int b_n4 = tid & 31, b_kb = (tid >> 5) * 4;   // B: 32 float4/row, 4-k group
    const float* We = W + (size_t)e * D_DIM * D_DIM + n0;

    int rowtok[4];
    #pragma unroll
    for (int i = 0; i < 4; i++) {
        int gm = m0 + a_r0 + 32 * i;
        rowtok[i] = tl[gm < count ? gm : 0];
    }

    // prologue: stage k0=0 into buffer 0
    stage_tile(x, We, rowtok, 0, a_c4, a_r0, b_n4, b_kb, AlsBuf[0], BlsBuf[0]);
    __syncthreads();

    int cur = 0;
    for (int k0 = 0; k0 < D_DIM; k0 += 32) {
        int nxt = cur ^ 1;
        if (k0 + 32 < D_DIM)
            stage_tile(x, We, rowtok, k0 + 32, a_c4, a_r0, b_n4, b_kb,
                       AlsBuf[nxt], BlsBuf[nxt]);

        const short* Als = AlsBuf[cur];
        const short* Bls = BlsBuf[cur];
        short8 af[4], bfr[4];
        #pragma unroll
        for (int i = 0; i < 4; i++)
            af[i] = *(const short8*)&Als[(mB + 16 * i + l16) * 40 + quad * 8];
        #pragma unroll
        for (int j = 0; j < 4; j++)
            bfr[j] = *(const short8*)&Bls[(nB + 16 * j + l16) * 40 + quad * 8];
        #pragma unroll
        for (int i = 0; i < 4; i++)
            #pragma unroll
            for (int j = 0; j < 4; j++)
                accf[i][j] = __builtin_amdgcn_mfma_f32_16x16x32_bf16(af[i], bfr[j], accf[i][j], 0, 0, 0);

        __syncthreads();   // next-buffer writes done; cur-buffer reads done
        cur = nxt;
    }

    // ---- epilogue: (acc + bias) * top_prob, scatter rows ----
    float bv[4];
    #pragma unroll
    for (int j = 0; j < 4; j++)
        bv[j] = bias[e * D_DIM + n0 + nB + 16 * j + l16];

    #pragma unroll
    for (int i = 0; i < 4; i++) {
        int rb = m0 + mB + 16 * i + quad * 4;
        #pragma unroll
        for (int r = 0; r < 4; r++) {
            int gm = rb + r;
            if (gm >= count) continue;
            int tok = tl[gm];
            float p = top_prob[tok];
            float* orow = out + (size_t)tok * D_DIM + n0 + nB + l16;
            #pragma unroll
            for (int j = 0; j < 4; j++)
                orow[16 * j] = (accf[i][j][r] + bv[j]) * p;
        }
    }
}

// ---------------- aux loss ----------------
__global__ void aux_kernel(const float* __restrict__ ppart, const float* __restrict__ fpart,
                           float* __restrict__ out_aux) {
    int lane = threadIdx.x;           // 64 = NBIN
    float p[8], f[8];
    #pragma unroll
    for (int e = 0; e < 8; e++) { p[e] = ppart[lane * 8 + e]; f[e] = fpart[lane * 8 + e]; }
    #pragma unroll
    for (int off = 32; off > 0; off >>= 1) {
        #pragma unroll
        for (int e = 0; e < 8; e++) {
            p[e] += __shfl_xor(p[e], off, 64);
            f[e] += __shfl_xor(f[e], off, 64);
        }
    }
    if (lane == 0) {
        float s = 0.f;
        #pragma unroll
        for (int e = 0; e < 8; e++)
            s += (f[e] / (float)T_TOK) * (p[e] / (float)T_TOK);
        out_aux[0] = (float)E_EXP * s;
    }
}

extern "C" void kernel_launch(void* const* d_in, const int* in_sizes, int n_in,
                              void* d_out, int out_size, void* d_ws, size_t ws_size,
                              hipStream_t stream) {
    const float* x  = (const float*)d_in[0];   // [4096,1024]
    const float* Wg = (const float*)d_in[1];   // [1024,8]
    const float* bg = (const float*)d_in[2];   // [8]
    const float* W  = (const float*)d_in[3];   // [8,1024,1024]
    const float* b  = (const float*)d_in[4];   // [8,1024]
    float* out = (float*)d_out;                // [4096*1024 + 1]

    char* ws = (char*)d_ws;                    // total 57,376 B used
    int*   top_idx  = (int*)(ws + 0);              // 16384 B
    float* top_prob = (float*)(ws + 16384);        // 16384 B
    int*   tok_list = (int*)(ws + 32768);          // 20480 B (8*640)
    int*   cnt      = (int*)(ws + 53248);          // 32 B
    float* ppart    = (float*)(ws + 53280);        // 2048 B (64*8)
    float* fpart    = (float*)(ws + 55328);        // 2048 B

    hipLaunchKernelGGL(zero_out_kernel, dim3(T_TOK * D_DIM / 4 / 256), dim3(256), 0, stream,
                       out, ppart, fpart);
    hipLaunchKernelGGL(gating_kernel, dim3(T_TOK / 4), dim3(256), 0, stream,
                       x, Wg, bg, top_idx, top_prob, ppart, fpart);
    hipLaunchKernelGGL(scan_kernel, dim3(1), dim3(64), 0, stream,
                       top_idx, tok_list, cnt);
    hipLaunchKernelGGL(expert_gemm, dim3(E_EXP * 5 * 8), dim3(256), 0, stream,
                       x, W, b, tok_list, cnt, top_prob, out);
    hipLaunchKernelGGL(aux_kernel, dim3(1), dim3(64), 0, stream, ppart, fpart,
                       out + (size_t)T_TOK * D_DIM);
}

// Round 3
// 171.906 us; speedup vs baseline: 1.1529x; 1.1529x over previous
//
#include <hip/hip_runtime.h>
#include <hip/hip_bf16.h>
#include <cstdint>

#define T_TOK 4096
#define D_DIM 1024
#define E_EXP 8
#define CAP   640          // int(1.25 * 4096 / 8)
#define NBIN  64
#define MAXDROP 3456       // worst case: all tokens -> one expert

typedef __attribute__((ext_vector_type(8))) short short8;
typedef __attribute__((ext_vector_type(4))) float f32x4;

// round-to-nearest-even float -> bf16 bits
__device__ inline unsigned short f2bf(float f) {
    uint32_t u = __float_as_uint(f);
    u += 0x7fffu + ((u >> 16) & 1u);
    return (unsigned short)(u >> 16);
}

// ---------------- gating: logits, softmax, argmax, binned P sums ----------------
__global__ __launch_bounds__(256) void gating_kernel(
    const float* __restrict__ x, const float* __restrict__ Wg,
    const float* __restrict__ bg,
    int* __restrict__ top_idx, float* __restrict__ top_prob,
    float* __restrict__ ppart)
{
    int wid  = threadIdx.x >> 6;
    int lane = threadIdx.x & 63;
    int t = blockIdx.x * 4 + wid;     // one wave per token

    float acc[8];
    #pragma unroll
    for (int e = 0; e < 8; e++) acc[e] = 0.f;

    const float* xr = x + (size_t)t * D_DIM;
    #pragma unroll 4
    for (int i = 0; i < 16; i++) {
        int d = lane + 64 * i;
        float xv = xr[d];
        const float4* wr = (const float4*)(Wg + (size_t)d * 8);
        float4 w0 = wr[0], w1 = wr[1];
        acc[0] += xv * w0.x; acc[1] += xv * w0.y;
        acc[2] += xv * w0.z; acc[3] += xv * w0.w;
        acc[4] += xv * w1.x; acc[5] += xv * w1.y;
        acc[6] += xv * w1.z; acc[7] += xv * w1.w;
    }
    #pragma unroll
    for (int off = 32; off > 0; off >>= 1) {
        #pragma unroll
        for (int e = 0; e < 8; e++) acc[e] += __shfl_xor(acc[e], off, 64);
    }

    if (lane == 0) {
        float lg[8];
        #pragma unroll
        for (int e = 0; e < 8; e++) lg[e] = acc[e] + bg[e];
        float m = lg[0]; int am = 0;
        #pragma unroll
        for (int e = 1; e < 8; e++) { if (lg[e] > m) { m = lg[e]; am = e; } }
        float ex[8], s = 0.f;
        #pragma unroll
        for (int e = 0; e < 8; e++) { ex[e] = expf(lg[e] - m); s += ex[e]; }
        float inv = 1.f / s;
        top_idx[t]  = am;
        top_prob[t] = ex[am] * inv;
        int bin = (int)(blockIdx.x & (NBIN - 1));
        #pragma unroll
        for (int e = 0; e < 8; e++) atomicAdd(&ppart[bin * 8 + e], ex[e] * inv);
    }
}

// ---------------- scan: hierarchical capacity dispatch, 1 block x 1024 thr ----------------
// phase1: per-chunk per-expert counts (16 waves x 4 chunks)
// phase2a: wave0 prefix-scans the 64 chunk-counts per expert
// phase2b: all waves place tokens; dropped rows zeroed cooperatively
__global__ __launch_bounds__(1024) void scan_kernel(
    const int* __restrict__ top_idx,
    int* __restrict__ tok_list, int* __restrict__ cnt, int* __restrict__ fullcnt,
    float* __restrict__ out)
{
    __shared__ int counts[64][8];
    __shared__ int excl[64][8];
    __shared__ int droplist[MAXDROP];
    __shared__ int ndrop;

    int tid  = threadIdx.x;
    int wv   = tid >> 6;
    int lane = tid & 63;
    unsigned long long ltmask = (lane == 0) ? 0ull : ((~0ull) >> (64 - lane));

    if (tid == 0) ndrop = 0;

    int ecache[4];
    #pragma unroll
    for (int c = 0; c < 4; c++)
        ecache[c] = top_idx[(4 * wv + c) * 64 + lane];

    #pragma unroll
    for (int c = 0; c < 4; c++) {
        int chunk = 4 * wv + c;
        int e = ecache[c];
        #pragma unroll
        for (int q = 0; q < 8; q++) {
            unsigned long long mk = __ballot(e == q);
            int tot = __popcll(mk);
            if (lane == q) counts[chunk][q] = tot;
        }
    }
    __syncthreads();

    if (wv == 0) {
        #pragma unroll
        for (int q = 0; q < 8; q++) {
            int v = counts[lane][q];
            int orig = v;
            #pragma unroll
            for (int off = 1; off < 64; off <<= 1) {
                int n = __shfl_up(v, off, 64);
                if (lane >= off) v += n;
            }
            excl[lane][q] = v - orig;
            int total = __shfl(v, 63, 64);
            if (lane == 0) {
                fullcnt[q] = total;
                cnt[q] = total < CAP ? total : CAP;
            }
        }
    }
    __syncthreads();

    #pragma unroll
    for (int c = 0; c < 4; c++) {
        int chunk = 4 * wv + c;
        int t = chunk * 64 + lane;
        int e = ecache[c];
        int pos = 0;
        #pragma unroll
        for (int q = 0; q < 8; q++) {
            unsigned long long mk = __ballot(e == q);
            if (e == q) pos = excl[chunk][q] + __popcll(mk & ltmask);
        }
        if (pos < CAP) {
            tok_list[e * CAP + pos] = t;
        } else {
            int di = atomicAdd(&ndrop, 1);
            droplist[di] = t;
        }
    }
    __syncthreads();

    // zero dropped rows of out (expected ~0 rows); 4 rows at a time, 256 thr/row
    int nd = ndrop;
    int grp = tid >> 8;          // 0..3
    int col = (tid & 255) * 4;
    float4 z = {0.f, 0.f, 0.f, 0.f};
    for (int d = grp; d < nd; d += 4) {
        int row = droplist[d];
        *(float4*)&out[(size_t)row * D_DIM + col] = z;
    }
}

// ---------------- staging helper: global fp32 -> LDS bf16 ----------------
__device__ inline void stage_tile(const float* __restrict__ x,
                                  const float* __restrict__ We, int n0,
                                  const int* rowtok, int k0,
                                  int a_c4, int a_r0, int b_c4, int b_kk,
                                  short* Als, short* Bls)
{
    // A: gathered token rows, [m][k] stride 40, 128 rows x 32 k
    #pragma unroll
    for (int i = 0; i < 4; i++) {
        const float4 xv = *(const float4*)(x + (size_t)rowtok[i] * D_DIM + k0 + 4 * a_c4);
        ushort4 us;
        us.x = f2bf(xv.x); us.y = f2bf(xv.y); us.z = f2bf(xv.z); us.w = f2bf(xv.w);
        *(ushort4*)&Als[(a_r0 + 32 * i) * 40 + 4 * a_c4] = us;
    }
    // B transposed: [n][k] stride 40, 64 cols x 32 k; thread: 4 cols x 2 k
    const float* wp = We + (size_t)(k0 + b_kk) * D_DIM + n0 + 4 * b_c4;
    float4 w0 = *(const float4*)(wp);
    float4 w1 = *(const float4*)(wp + D_DIM);
    ushort2 u;
    u.x = f2bf(w0.x); u.y = f2bf(w1.x);
    *(ushort2*)&Bls[(4 * b_c4 + 0) * 40 + b_kk] = u;
    u.x = f2bf(w0.y); u.y = f2bf(w1.y);
    *(ushort2*)&Bls[(4 * b_c4 + 1) * 40 + b_kk] = u;
    u.x = f2bf(w0.z); u.y = f2bf(w1.z);
    *(ushort2*)&Bls[(4 * b_c4 + 2) * 40 + b_kk] = u;
    u.x = f2bf(w0.w); u.y = f2bf(w1.w);
    *(ushort2*)&Bls[(4 * b_c4 + 3) * 40 + b_kk] = u;
}

// ---------------- expert GEMM: bf16 MFMA 128x64 tile, double-buffered LDS ----------------
// 640 blocks (8e x 5mt x 16nt), 30 KB LDS -> ~2.5 blocks/CU grid-limited, 10 waves/CU
__global__ __launch_bounds__(256) void expert_gemm(
    const float* __restrict__ x, const float* __restrict__ W,
    const float* __restrict__ bias,
    const int* __restrict__ tok_list, const int* __restrict__ cnt,
    const float* __restrict__ top_prob, float* __restrict__ out)
{
    int bid = blockIdx.x;
    int e   = bid / 80;               // 5 mt * 16 nt = 80 per expert
    int rem = bid % 80;
    int mt  = rem / 16, nt = rem % 16;
    int count = cnt[e];
    int m0 = mt * 128;
    if (m0 >= count) return;
    int n0 = nt * 64;

    __shared__ __attribute__((aligned(16))) short AlsBuf[2][128 * 40]; // 20 KB
    __shared__ __attribute__((aligned(16))) short BlsBuf[2][64 * 40];  // 10 KB

    int tid  = threadIdx.x;
    int lane = tid & 63, wid = tid >> 6;
    int quad = lane >> 4, l16 = lane & 15;
    int mB = (wid >> 1) * 64, nB = (wid & 1) * 32;

    f32x4 accf[4][2];
    #pragma unroll
    for (int i = 0; i < 4; i++)
        #pragma unroll
        for (int j = 0; j < 2; j++)
            accf[i][j] = (f32x4){0.f, 0.f, 0.f, 0.f};

    const int* tl = tok_list + e * CAP;
    int a_c4 = tid & 7,  a_r0 = tid >> 3;         // A: 8 float4/row, 32 rows/round
    int b_c4 = tid & 15, b_kk = (tid >> 4) * 2;   // B: 16 float4/k-row, 2 k/thread
    const float* We = W + (size_t)e * D_DIM * D_DIM;

    int rowtok[4];
    #pragma unroll
    for (int i = 0; i < 4; i++) {
        int gm = m0 + a_r0 + 32 * i;
        rowtok[i] = tl[gm < count ? gm : 0];
    }

    stage_tile(x, We, n0, rowtok, 0, a_c4, a_r0, b_c4, b_kk, AlsBuf[0], BlsBuf[0]);
    __syncthreads();

    int cur = 0;
    for (int k0 = 0; k0 < D_DIM; k0 += 32) {
        int nxt = cur ^ 1;
        if (k0 + 32 < D_DIM)
            stage_tile(x, We, n0, rowtok, k0 + 32, a_c4, a_r0, b_c4, b_kk,
                       AlsBuf[nxt], BlsBuf[nxt]);

        const short* Als = AlsBuf[cur];
        const short* Bls = BlsBuf[cur];
        short8 af[4], bfr[2];
        #pragma unroll
        for (int i = 0; i < 4; i++)
            af[i] = *(const short8*)&Als[(mB + 16 * i + l16) * 40 + quad * 8];
        #pragma unroll
        for (int j = 0; j < 2; j++)
            bfr[j] = *(const short8*)&Bls[(nB + 16 * j + l16) * 40 + quad * 8];
        #pragma unroll
        for (int i = 0; i < 4; i++)
            #pragma unroll
            for (int j = 0; j < 2; j++)
                accf[i][j] = __builtin_amdgcn_mfma_f32_16x16x32_bf16(af[i], bfr[j], accf[i][j], 0, 0, 0);

        __syncthreads();   // nxt writes done; cur reads done
        cur = nxt;
    }

    // ---- epilogue: (acc + bias) * top_prob, scatter rows ----
    float bv[2];
    #pragma unroll
    for (int j = 0; j < 2; j++)
        bv[j] = bias[e * D_DIM + n0 + nB + 16 * j + l16];

    #pragma unroll
    for (int i = 0; i < 4; i++) {
        int rb = m0 + mB + 16 * i + quad * 4;
        #pragma unroll
        for (int r = 0; r < 4; r++) {
            int gm = rb + r;
            if (gm >= count) continue;
            int tok = tl[gm];
            float p = top_prob[tok];
            float* orow = out + (size_t)tok * D_DIM + n0 + nB + l16;
            #pragma unroll
            for (int j = 0; j < 2; j++)
                orow[16 * j] = (accf[i][j][r] + bv[j]) * p;
        }
    }
}

// ---------------- aux loss ----------------
__global__ void aux_kernel(const float* __restrict__ ppart, const int* __restrict__ fullcnt,
                           float* __restrict__ out_aux) {
    int lane = threadIdx.x;           // 64 = NBIN
    float p[8];
    #pragma unroll
    for (int e = 0; e < 8; e++) p[e] = ppart[lane * 8 + e];
    #pragma unroll
    for (int off = 32; off > 0; off >>= 1) {
        #pragma unroll
        for (int e = 0; e < 8; e++) p[e] += __shfl_xor(p[e], off, 64);
    }
    if (lane == 0) {
        float s = 0.f;
        #pragma unroll
        for (int e = 0; e < 8; e++)
            s += ((float)fullcnt[e] / (float)T_TOK) * (p[e] / (float)T_TOK);
        out_aux[0] = (float)E_EXP * s;
    }
}

extern "C" void kernel_launch(void* const* d_in, const int* in_sizes, int n_in,
                              void* d_out, int out_size, void* d_ws, size_t ws_size,
                              hipStream_t stream) {
    const float* x  = (const float*)d_in[0];   // [4096,1024]
    const float* Wg = (const float*)d_in[1];   // [1024,8]
    const float* bg = (const float*)d_in[2];   // [8]
    const float* W  = (const float*)d_in[3];   // [8,1024,1024]
    const float* b  = (const float*)d_in[4];   // [8,1024]
    float* out = (float*)d_out;                // [4096*1024 + 1]

    char* ws = (char*)d_ws;                    // 55,360 B used
    int*   top_idx  = (int*)(ws + 0);              // 16384 B
    float* top_prob = (float*)(ws + 16384);        // 16384 B
    int*   tok_list = (int*)(ws + 32768);          // 20480 B (8*640)
    int*   cnt      = (int*)(ws + 53248);          // 32 B
    int*   fullcnt  = (int*)(ws + 53280);          // 32 B
    float* ppart    = (float*)(ws + 53312);        // 2048 B (64*8)

    hipMemsetAsync(ppart, 0, NBIN * 8 * sizeof(float), stream);
    hipLaunchKernelGGL(gating_kernel, dim3(T_TOK / 4), dim3(256), 0, stream,
                       x, Wg, bg, top_idx, top_prob, ppart);
    hipLaunchKernelGGL(scan_kernel, dim3(1), dim3(1024), 0, stream,
                       top_idx, tok_list, cnt, fullcnt, out);
    hipLaunchKernelGGL(expert_gemm, dim3(E_EXP * 5 * 16), dim3(256), 0, stream,
                       x, W, b, tok_list, cnt, top_prob, out);
    hipLaunchKernelGGL(aux_kernel, dim3(1), dim3(64), 0, stream, ppart, fullcnt,
                       out + (size_t)T_TOK * D_DIM);
}